// Round 7
// baseline (264.264 us; speedup 1.0000x reference)
//
#include <hip/hip_runtime.h>
#include <stdint.h>

// T5-style attention, MI355X gfx950.
// B=2 S=2048 D=1024 H=16 DK=64, NUM_BUCKETS=32, MAX_DISTANCE=128.
// R7: flash v6 — K/V fragments loaded DIRECTLY from global (no LDS tiles, no
// in-loop barriers); LDS only for bias window + wave-local P round-trip.
// kf double-buffered in regs; vf issued early, waited at PV.

typedef unsigned short u16;
typedef __attribute__((ext_vector_type(8))) short short8;
typedef __attribute__((ext_vector_type(4))) float float4v;
typedef __attribute__((ext_vector_type(4))) u16 ushort4v;

typedef __attribute__((address_space(1))) void void_g;
typedef __attribute__((address_space(3))) void void_l;

#define L2E 1.4426950408889634f

__device__ __forceinline__ u16 f2b(float f) {
  union { float f; uint32_t u; } v; v.f = f;
  uint32_t r = (v.u + 0x7fffu + ((v.u >> 16) & 1u)) >> 16;
  return (u16)r;
}
__device__ __forceinline__ u16 f2b_fast(float f) {
  union { float f; uint32_t u; } v; v.f = f;
  return (u16)((v.u + 0x8000u) >> 16);
}

// ---------------- fused fp32 -> bf16 convert -----------------------------------
__global__ void cvt_all(const float* __restrict__ x,  const float* __restrict__ qw,
                        const float* __restrict__ kw, const float* __restrict__ vw,
                        const float* __restrict__ ow,
                        u16* __restrict__ xb, u16* __restrict__ wqkv, u16* __restrict__ owb) {
  int i = blockIdx.x * blockDim.x + threadIdx.x;
  const float* s; u16* d; int off;
  if (i < 1048576)      { s = x;  d = xb;              off = i; }
  else if (i < 1310720) { s = qw; d = wqkv;            off = i - 1048576; }
  else if (i < 1572864) { s = kw; d = wqkv + 1048576;  off = i - 1310720; }
  else if (i < 1835008) { s = vw; d = wqkv + 2097152;  off = i - 1572864; }
  else                  { s = ow; d = owb;             off = i - 1835008; }
  float4v v = ((const float4v*)s)[off];
  ushort4v o;
  o.x = f2b(v.x); o.y = f2b(v.y); o.z = f2b(v.z); o.w = f2b(v.w);
  ((ushort4v*)d)[off] = o;
}

// ---------------- bias table: biasT[h][d+2047] = (bias - 8) * log2e ------------
__global__ void build_bias(const float* __restrict__ rel_bias, float* __restrict__ biasT) {
  int idx = blockIdx.x * blockDim.x + threadIdx.x; // 16 * 4096
  int h = idx >> 12, t = idx & 4095;
  if (t > 4094) { biasT[h * 4096 + 4095] = -1.0e4f; return; }  // loaded, never used
  int d = t - 2047;
  int n = -d;
  int ret = (n < 0) ? 16 : 0;
  int na = (n < 0) ? -n : n;
  int bucket;
  if (na < 8) {
    bucket = ret + na;
  } else {
    float v = logf((float)na / 8.0f) / logf(16.0f) * 8.0f;
    int vi = 8 + (int)v;
    bucket = ret + (vi > 15 ? 15 : vi);
  }
  biasT[h * 4096 + t] = (rel_bias[bucket * 16 + h] - 8.0f) * L2E;
}

// ---------------- bf16 GEMM: C[M,N] = A[M,K] * W[N,K]^T ------------------------
template<bool OUT_BF16>
__global__ __launch_bounds__(256, 2)
void gemm_bt(const u16* __restrict__ A, const u16* __restrict__ W,
             void* __restrict__ Cp, int K, int N) {
  __shared__ __align__(16) u16 As[128 * 32];
  __shared__ __align__(16) u16 Bs[128 * 32];
  const int tid = threadIdx.x;
  const int wid = tid >> 6;
  const int lane = tid & 63;
  const int row16 = lane & 15, oct = lane >> 4;
  const int tm = blockIdx.x * 128, tn = blockIdx.y * 128;
  const int wm = (wid & 1) * 64, wn = (wid >> 1) * 64;
  float4v acc[4][4] = {};
  for (int k0 = 0; k0 < K; k0 += 32) {
    __syncthreads();
#pragma unroll
    for (int i = 0; i < 2; i++) {
      const int fo = (i * 256 + tid) * 8;
      const int r = fo >> 5, c = fo & 31;
      __builtin_amdgcn_global_load_lds((void_g*)(A + (size_t)(tm + r) * K + k0 + c),
                                       (void_l*)(As + (i * 256 + wid * 64) * 8), 16, 0, 0);
      __builtin_amdgcn_global_load_lds((void_g*)(W + (size_t)(tn + r) * K + k0 + c),
                                       (void_l*)(Bs + (i * 256 + wid * 64) * 8), 16, 0, 0);
    }
    __syncthreads();
    short8 af[4], bfr[4];
#pragma unroll
    for (int mi = 0; mi < 4; mi++)
      af[mi] = *(const short8*)(As + (wm + mi * 16 + row16) * 32 + oct * 8);
#pragma unroll
    for (int ni = 0; ni < 4; ni++)
      bfr[ni] = *(const short8*)(Bs + (wn + ni * 16 + row16) * 32 + oct * 8);
#pragma unroll
    for (int mi = 0; mi < 4; mi++)
#pragma unroll
      for (int ni = 0; ni < 4; ni++)
        acc[mi][ni] = __builtin_amdgcn_mfma_f32_16x16x32_bf16(af[mi], bfr[ni], acc[mi][ni], 0, 0, 0);
  }
#pragma unroll
  for (int mi = 0; mi < 4; mi++) {
    const int rbase = tm + wm + mi * 16 + oct * 4;
#pragma unroll
    for (int ni = 0; ni < 4; ni++) {
      const int col = tn + wn + ni * 16 + row16;
#pragma unroll
      for (int r = 0; r < 4; r++) {
        size_t idx = (size_t)(rbase + r) * N + col;
        if (OUT_BF16) ((u16*)Cp)[idx] = f2b(acc[mi][ni][r]);
        else          ((float*)Cp)[idx] = acc[mi][ni][r];
      }
    }
  }
}

// ---------------- V transpose + k-permutation ----------------------------------
// QKV V-section [b][s][h*64+d] -> vTp[b][h][d][s'], kappa = 2*(s&15)+((s>>4)&1)
__global__ __launch_bounds__(256, 2)
void transpose_v(const u16* __restrict__ QKV, u16* __restrict__ vTp) {
  const int s0 = blockIdx.x * 64, h = blockIdx.y, b = blockIdx.z;
  const int tid = threadIdx.x;
  __shared__ u16 T[64 * 73];
  const u16* src = QKV + 2048 + (size_t)b * 2048 * 3072 + h * 64;
#pragma unroll
  for (int it = 0; it < 2; it++) {
    int idx = it * 256 + tid;
    int sl = idx >> 3;
    int c = idx & 7;
    short8 v = *(const short8*)(src + (size_t)(s0 + sl) * 3072 + c * 8);
#pragma unroll
    for (int k = 0; k < 8; k++) T[(c * 8 + k) * 73 + sl] = (u16)v[k];
  }
  __syncthreads();
  u16* dst = vTp + ((size_t)(b * 16 + h) * 64) * 2048 + s0;
#pragma unroll
  for (int it = 0; it < 2; it++) {
    int idx = it * 256 + tid;
    int d = idx >> 3;
    int cs = idx & 7;
    short8 o;
#pragma unroll
    for (int k = 0; k < 8; k++) {
      int sp = cs * 8 + k;
      int sl = (sp & 32) + 16 * (sp & 1) + ((sp & 31) >> 1);
      o[k] = (short)T[d * 73 + sl];
    }
    *(short8*)(dst + (size_t)d * 2048 + cs * 8) = o;
  }
}

// ---------------- flash attention v6 -------------------------------------------
// grid (S/128, H, B), block 256 = 4 waves; wave owns 32 q-rows (2 q-frags).
// K/V fragments loaded directly from global (B-frag layout). No in-loop
// barriers. Static softmax max 8, exp2-folded bias ((b-8)*log2e in table).
__global__ __launch_bounds__(256, 2)
void flash_attn(const u16* __restrict__ QKV, const u16* __restrict__ vTp,
                const float* __restrict__ biasT, u16* __restrict__ ctx) {
  const int S = 2048, LDQ = 3072;
  const int qt0 = blockIdx.x * 128;
  const int h = blockIdx.y, b = blockIdx.z;
  const int tid = threadIdx.x, wid = tid >> 6, lane = tid & 63;
  const int row16 = lane & 15, oct = lane >> 4;

  __shared__ __align__(16) float biasS[2176];        // 8.5 KB (pre *log2e, -8 folded)
  __shared__ __align__(16) u16 Pl[4][2][16][40];     // 10 KB per-wave P staging

  {
    const float* bsrc = biasT + h * 4096 + (1920 - qt0);
    for (int i = tid; i < 544; i += 256)
      ((float4v*)biasS)[i] = ((const float4v*)bsrc)[i];
  }

  // Q fragments: 2 q-frags x 2 d-halves
  const u16* qbase = QKV + ((size_t)b * S + qt0 + wid * 32) * LDQ + h * 64;
  short8 qf[2][2];
#pragma unroll
  for (int f = 0; f < 2; f++)
#pragma unroll
    for (int hd = 0; hd < 2; hd++)
      qf[f][hd] = *(const short8*)(qbase + (size_t)(f * 16 + row16) * LDQ + hd * 32 + oct * 8);

  __syncthreads();  // biasS ready (only barrier in the kernel)

  float l_r[2][4] = {};
  float4v o_acc[2][4] = {};

  // direct-fragment base pointers (per-lane)
  const u16* Kf0 = QKV + 1024 + ((size_t)b * S + row16) * LDQ + h * 64 + oct * 8;
  const u16* Vf0 = vTp + ((size_t)(b * 16 + h) * 64 + row16) * 2048 + oct * 8;

  short8 kfA[4][2], kfB[4][2];
#pragma unroll
  for (int st = 0; st < 4; st++)
#pragma unroll
    for (int hd = 0; hd < 2; hd++)
      kfA[st][hd] = *(const short8*)(Kf0 + (size_t)(st * 16) * LDQ + hd * 32);

  auto step = [&](short8 (&cur)[4][2], short8 (&nxt)[4][2], int ktc, bool pfk) {
    // vf loads issued first (waited only at PV)
    short8 vf[2][4];
#pragma unroll
    for (int ni = 0; ni < 4; ni++)
#pragma unroll
      for (int ks = 0; ks < 2; ks++)
        vf[ks][ni] = *(const short8*)(Vf0 + (size_t)ni * 32768 + ktc + ks * 32);

    // QK scores (waits cur kf)
    float4v sc[2][4];
#pragma unroll
    for (int f = 0; f < 2; f++)
#pragma unroll
      for (int st = 0; st < 4; st++) {
        float4v s = {};
        s = __builtin_amdgcn_mfma_f32_16x16x32_bf16(qf[f][0], cur[st][0], s, 0, 0, 0);
        s = __builtin_amdgcn_mfma_f32_16x16x32_bf16(qf[f][1], cur[st][1], s, 0, 0, 0);
        sc[f][st] = s;
      }

    // prefetch next-step K fragments (latency hidden under exp/PV)
    if (pfk) {
#pragma unroll
      for (int st = 0; st < 4; st++)
#pragma unroll
        for (int hd = 0; hd < 2; hd++)
          nxt[st][hd] = *(const short8*)(Kf0 + (size_t)(ktc + 64 + st * 16) * LDQ + hd * 32);
    }

    // exp2(fma) + P-store + l-accum + PV, f-interleaved
#pragma unroll
    for (int f = 0; f < 2; f++) {
      const int base = ktc + row16 - wid * 32 - f * 16 - oct * 4 + 127;
#pragma unroll
      for (int r = 0; r < 4; r++) {
        const int i0 = base - r;
        float b0 = biasS[i0],      b1 = biasS[i0 + 16];
        float b2 = biasS[i0 + 32], b3 = biasS[i0 + 48];
        sc[f][0][r] = __builtin_amdgcn_exp2f(__builtin_fmaf(sc[f][0][r], L2E, b0));
        sc[f][1][r] = __builtin_amdgcn_exp2f(__builtin_fmaf(sc[f][1][r], L2E, b1));
        sc[f][2][r] = __builtin_amdgcn_exp2f(__builtin_fmaf(sc[f][2][r], L2E, b2));
        sc[f][3][r] = __builtin_amdgcn_exp2f(__builtin_fmaf(sc[f][3][r], L2E, b3));
      }
#pragma unroll
      for (int ks = 0; ks < 2; ks++)
#pragma unroll
        for (int r = 0; r < 4; r++) {
          uint32_t pk = (uint32_t)f2b_fast(sc[f][2 * ks][r]) |
                        ((uint32_t)f2b_fast(sc[f][2 * ks + 1][r]) << 16);
          *(uint32_t*)&Pl[wid][ks][oct * 4 + r][2 * row16] = pk;
        }
#pragma unroll
      for (int r = 0; r < 4; r++)
        l_r[f][r] += (sc[f][0][r] + sc[f][1][r]) + (sc[f][2][r] + sc[f][3][r]);
      // wave-local in-order DS: read back as A-frags (waits vf at first MFMA)
#pragma unroll
      for (int ks = 0; ks < 2; ks++) {
        short8 pf = *(const short8*)&Pl[wid][ks][row16][oct * 8];
#pragma unroll
        for (int ni = 0; ni < 4; ni++)
          o_acc[f][ni] = __builtin_amdgcn_mfma_f32_16x16x32_bf16(pf, vf[ks][ni], o_acc[f][ni], 0, 0, 0);
      }
    }
  };

  for (int kt = 0; kt < S; kt += 128) {
    step(kfA, kfB, kt, true);                 // prefetches kt+64 into kfB
    step(kfB, kfA, kt + 64, kt + 128 < S);    // prefetches kt+128 into kfA
  }

  // normalize + store
#pragma unroll
  for (int f = 0; f < 2; f++) {
#pragma unroll
    for (int r = 0; r < 4; r++) {
      float v = l_r[f][r];
      v += __shfl_xor(v, 1); v += __shfl_xor(v, 2);
      v += __shfl_xor(v, 4); v += __shfl_xor(v, 8);
      l_r[f][r] = 1.0f / v;
    }
    const size_t orow = (size_t)b * S + qt0 + wid * 32 + f * 16 + oct * 4;
#pragma unroll
    for (int ni = 0; ni < 4; ni++)
#pragma unroll
      for (int r = 0; r < 4; r++)
        ctx[(orow + r) * 1024 + h * 64 + ni * 16 + row16] = f2b_fast(o_acc[f][ni][r] * l_r[f][r]);
  }
}

// ---------------- host launcher ------------------------------------------------
extern "C" void kernel_launch(void* const* d_in, const int* in_sizes, int n_in,
                              void* d_out, int out_size, void* d_ws, size_t ws_size,
                              hipStream_t stream) {
  const float* x        = (const float*)d_in[0];
  const float* q_w      = (const float*)d_in[1];
  const float* k_w      = (const float*)d_in[2];
  const float* v_w      = (const float*)d_in[3];
  const float* o_w      = (const float*)d_in[4];
  const float* rel_bias = (const float*)d_in[5];

  char* ws = (char*)d_ws;
  u16*   xb    = (u16*)(ws);                         // 8 MB
  u16*   wqkv  = (u16*)(ws + 8388608);               // 6 MB
  u16*   owb   = (u16*)(ws + 14680064);              // 2 MB
  u16*   qkvb  = (u16*)(ws + 16777216);              // 24 MB
  u16*   ctxb  = (u16*)(ws + 41943040);              // 8 MB
  float* biasT = (float*)(ws + 50331648);            // 256 KB
  u16*   vTp   = xb;                                 // reuse xb after QKV GEMM

  cvt_all<<<8192, 256, 0, stream>>>(x, q_w, k_w, v_w, o_w, xb, wqkv, owb);
  build_bias<<<256, 256, 0, stream>>>(rel_bias, biasT);

  dim3 g1(4096 / 128, 3072 / 128);
  gemm_bt<true><<<g1, 256, 0, stream>>>(xb, wqkv, qkvb, 1024, 3072);

  dim3 gt(2048 / 64, 16, 2);
  transpose_v<<<gt, 256, 0, stream>>>(qkvb, vTp);

  dim3 g2(2048 / 128, 16, 2);
  flash_attn<<<g2, 256, 0, stream>>>(qkvb, vTp, biasT, ctxb);

  dim3 g3(4096 / 128, 1024 / 128);
  gemm_bt<false><<<g3, 256, 0, stream>>>(ctxb, owb, d_out, 1024, 1024);
}

// Round 8
// 204.760 us; speedup vs baseline: 1.2906x; 1.2906x over previous
//
#include <hip/hip_runtime.h>
#include <stdint.h>

// T5-style attention, MI355X gfx950.
// B=2 S=2048 D=1024 H=16 DK=64, NUM_BUCKETS=32, MAX_DISTANCE=128.
// R8: flash reverted to R6 (best: 65.6us). GEMM epilogues rewritten to
// LDS-staged coalesced b128 stores (was 64 scalar stores/lane).

typedef unsigned short u16;
typedef __attribute__((ext_vector_type(8))) short short8;
typedef __attribute__((ext_vector_type(4))) float float4v;
typedef __attribute__((ext_vector_type(4))) u16 ushort4v;

typedef __attribute__((address_space(1))) void void_g;
typedef __attribute__((address_space(3))) void void_l;

#define L2E 1.4426950408889634f

__device__ __forceinline__ u16 f2b(float f) {
  union { float f; uint32_t u; } v; v.f = f;
  uint32_t r = (v.u + 0x7fffu + ((v.u >> 16) & 1u)) >> 16;
  return (u16)r;
}
__device__ __forceinline__ u16 f2b_fast(float f) {
  union { float f; uint32_t u; } v; v.f = f;
  return (u16)((v.u + 0x8000u) >> 16);
}

// ---------------- fused fp32 -> bf16 convert -----------------------------------
__global__ void cvt_all(const float* __restrict__ x,  const float* __restrict__ qw,
                        const float* __restrict__ kw, const float* __restrict__ vw,
                        const float* __restrict__ ow,
                        u16* __restrict__ xb, u16* __restrict__ wqkv, u16* __restrict__ owb) {
  int i = blockIdx.x * blockDim.x + threadIdx.x;
  const float* s; u16* d; int off;
  if (i < 1048576)      { s = x;  d = xb;              off = i; }
  else if (i < 1310720) { s = qw; d = wqkv;            off = i - 1048576; }
  else if (i < 1572864) { s = kw; d = wqkv + 1048576;  off = i - 1310720; }
  else if (i < 1835008) { s = vw; d = wqkv + 2097152;  off = i - 1572864; }
  else                  { s = ow; d = owb;             off = i - 1835008; }
  float4v v = ((const float4v*)s)[off];
  ushort4v o;
  o.x = f2b(v.x); o.y = f2b(v.y); o.z = f2b(v.z); o.w = f2b(v.w);
  ((ushort4v*)d)[off] = o;
}

// ---------------- bias table: biasT[h][d+2047] = (bias - 8) * log2e ------------
__global__ void build_bias(const float* __restrict__ rel_bias, float* __restrict__ biasT) {
  int idx = blockIdx.x * blockDim.x + threadIdx.x; // 16 * 4096
  int h = idx >> 12, t = idx & 4095;
  if (t > 4094) { biasT[h * 4096 + 4095] = -1.0e4f; return; }  // loaded, never used
  int d = t - 2047;
  int n = -d;
  int ret = (n < 0) ? 16 : 0;
  int na = (n < 0) ? -n : n;
  int bucket;
  if (na < 8) {
    bucket = ret + na;
  } else {
    float v = logf((float)na / 8.0f) / logf(16.0f) * 8.0f;
    int vi = 8 + (int)v;
    bucket = ret + (vi > 15 ? 15 : vi);
  }
  biasT[h * 4096 + t] = (rel_bias[bucket * 16 + h] - 8.0f) * L2E;
}

// ---------------- bf16 GEMM: C[M,N] = A[M,K] * W[N,K]^T ------------------------
// 128x128 tile; epilogue staged through LDS for coalesced b128 stores.
template<bool OUT_BF16>
__global__ __launch_bounds__(256, 2)
void gemm_bt(const u16* __restrict__ A, const u16* __restrict__ W,
             void* __restrict__ Cp, int K, int N) {
  __shared__ __align__(16) char SM[34816];  // As(8K)+Bs(8K) during K-loop; Es after
  u16* As = (u16*)SM;
  u16* Bs = (u16*)(SM + 8192);
  const int tid = threadIdx.x;
  const int wid = tid >> 6;
  const int lane = tid & 63;
  const int row16 = lane & 15, oct = lane >> 4;
  const int tm = blockIdx.x * 128, tn = blockIdx.y * 128;
  const int wm = (wid & 1) * 64, wn = (wid >> 1) * 64;
  float4v acc[4][4] = {};
  for (int k0 = 0; k0 < K; k0 += 32) {
    __syncthreads();
#pragma unroll
    for (int i = 0; i < 2; i++) {
      const int fo = (i * 256 + tid) * 8;
      const int r = fo >> 5, c = fo & 31;
      __builtin_amdgcn_global_load_lds((void_g*)(A + (size_t)(tm + r) * K + k0 + c),
                                       (void_l*)(As + (i * 256 + wid * 64) * 8), 16, 0, 0);
      __builtin_amdgcn_global_load_lds((void_g*)(W + (size_t)(tn + r) * K + k0 + c),
                                       (void_l*)(Bs + (i * 256 + wid * 64) * 8), 16, 0, 0);
    }
    __syncthreads();
    short8 af[4], bfr[4];
#pragma unroll
    for (int mi = 0; mi < 4; mi++)
      af[mi] = *(const short8*)(As + (wm + mi * 16 + row16) * 32 + oct * 8);
#pragma unroll
    for (int ni = 0; ni < 4; ni++)
      bfr[ni] = *(const short8*)(Bs + (wn + ni * 16 + row16) * 32 + oct * 8);
#pragma unroll
    for (int mi = 0; mi < 4; mi++)
#pragma unroll
      for (int ni = 0; ni < 4; ni++)
        acc[mi][ni] = __builtin_amdgcn_mfma_f32_16x16x32_bf16(af[mi], bfr[ni], acc[mi][ni], 0, 0, 0);
  }

  if (OUT_BF16) {
    // stage full 128x128 bf16 tile in LDS (pitch 136), then coalesced b128 out
    u16* Es = (u16*)SM;
    __syncthreads();  // As/Bs dead
#pragma unroll
    for (int mi = 0; mi < 4; mi++)
#pragma unroll
      for (int ni = 0; ni < 4; ni++)
#pragma unroll
        for (int r = 0; r < 4; r++)
          Es[(wm + mi * 16 + oct * 4 + r) * 136 + wn + ni * 16 + row16] = f2b(acc[mi][ni][r]);
    __syncthreads();
    u16* C = (u16*)Cp;
#pragma unroll
    for (int it = 0; it < 8; it++) {
      int idx = it * 256 + tid;           // 2048 chunks of 8 u16
      int row = idx >> 4, c = idx & 15;
      short8 v = *(const short8*)(Es + row * 136 + c * 8);
      *(short8*)(C + (size_t)(tm + row) * N + tn + c * 8) = v;
    }
  } else {
    // f32 out: two 64-row passes through LDS (pitch 132), coalesced dwordx4
    float* Ef = (float*)SM;
    float* C = (float*)Cp;
#pragma unroll
    for (int pass = 0; pass < 2; pass++) {
      __syncthreads();
      if ((wid & 1) == pass) {
#pragma unroll
        for (int mi = 0; mi < 4; mi++)
#pragma unroll
          for (int ni = 0; ni < 4; ni++)
#pragma unroll
            for (int r = 0; r < 4; r++)
              Ef[(mi * 16 + oct * 4 + r) * 132 + wn + ni * 16 + row16] = acc[mi][ni][r];
      }
      __syncthreads();
#pragma unroll
      for (int it = 0; it < 8; it++) {
        int idx = it * 256 + tid;         // 2048 chunks of 4 f32
        int row = idx >> 5, c = idx & 31;
        float4v v = *(const float4v*)(Ef + row * 132 + c * 4);
        *(float4v*)(C + (size_t)(tm + pass * 64 + row) * N + tn + c * 4) = v;
      }
    }
  }
}

// ---------------- V transpose + k-permutation ----------------------------------
// QKV V-section [b][s][h*64+d] -> vTp[b][h][d][s'], kappa = 2*(s&15)+((s>>4)&1)
__global__ __launch_bounds__(256, 2)
void transpose_v(const u16* __restrict__ QKV, u16* __restrict__ vTp) {
  const int s0 = blockIdx.x * 64, h = blockIdx.y, b = blockIdx.z;
  const int tid = threadIdx.x;
  __shared__ u16 T[64 * 73];
  const u16* src = QKV + 2048 + (size_t)b * 2048 * 3072 + h * 64;
#pragma unroll
  for (int it = 0; it < 2; it++) {
    int idx = it * 256 + tid;
    int sl = idx >> 3;
    int c = idx & 7;
    short8 v = *(const short8*)(src + (size_t)(s0 + sl) * 3072 + c * 8);
#pragma unroll
    for (int k = 0; k < 8; k++) T[(c * 8 + k) * 73 + sl] = (u16)v[k];
  }
  __syncthreads();
  u16* dst = vTp + ((size_t)(b * 16 + h) * 64) * 2048 + s0;
#pragma unroll
  for (int it = 0; it < 2; it++) {
    int idx = it * 256 + tid;
    int d = idx >> 3;
    int cs = idx & 7;
    short8 o;
#pragma unroll
    for (int k = 0; k < 8; k++) {
      int sp = cs * 8 + k;
      int sl = (sp & 32) + 16 * (sp & 1) + ((sp & 31) >> 1);
      o[k] = (short)T[d * 73 + sl];
    }
    *(short8*)(dst + (size_t)d * 2048 + cs * 8) = o;
  }
}

// ---------------- flash attention (R6 verbatim) --------------------------------
// grid (S/128, H, B), block 256 = 4 waves; wave owns 32 q-rows (2 q-frags).
// KT=64. Static softmax max 8, exp2-folded bias ((b-8)*log2e in table).
__global__ __launch_bounds__(256, 2)
void flash_attn(const u16* __restrict__ QKV, const u16* __restrict__ vTp,
                const float* __restrict__ biasT, u16* __restrict__ ctx) {
  const int S = 2048, LDQ = 3072;
  const int qt0 = blockIdx.x * 128;
  const int h = blockIdx.y, b = blockIdx.z;
  const int tid = threadIdx.x, wid = tid >> 6, lane = tid & 63;
  const int row16 = lane & 15, oct = lane >> 4;

  __shared__ __align__(16) float biasS[2176];
  __shared__ __align__(16) u16 Ks[2][64][40];
  __shared__ __align__(16) u16 Vts[2][64][40];
  __shared__ __align__(16) u16 Pl[4][2][16][40];

  {
    const float* bsrc = biasT + h * 4096 + (1920 - qt0);
    for (int i = tid; i < 544; i += 256)
      ((float4v*)biasS)[i] = ((const float4v*)bsrc)[i];
  }

  const u16* qbase = QKV + ((size_t)b * S + qt0 + wid * 32) * LDQ + h * 64;
  short8 qf[2][2];
#pragma unroll
  for (int f = 0; f < 2; f++)
#pragma unroll
    for (int hd = 0; hd < 2; hd++)
      qf[f][hd] = *(const short8*)(qbase + (size_t)(f * 16 + row16) * LDQ + hd * 32 + oct * 8);

  float l_r[2][4] = {};
  float4v o_acc[2][4] = {};

  const int sr = lane >> 2, c8 = (lane & 3) * 8;
  const int srow = wid * 16 + sr;
  const u16* Kst = QKV + 1024 + ((size_t)b * S + srow) * LDQ + h * 64 + c8;
  const u16* Vst = vTp + ((size_t)(b * 16 + h) * 64 + srow) * 2048 + c8;

  short8 kreg[2], vreg[2];
#pragma unroll
  for (int hd = 0; hd < 2; hd++) kreg[hd] = *(const short8*)(Kst + hd * 32);
#pragma unroll
  for (int ks = 0; ks < 2; ks++) vreg[ks] = *(const short8*)(Vst + ks * 32);

  for (int kt = 0; kt < S; kt += 64) {
    __syncthreads();
#pragma unroll
    for (int hd = 0; hd < 2; hd++) *(short8*)&Ks[hd][srow][c8] = kreg[hd];
#pragma unroll
    for (int ks = 0; ks < 2; ks++) *(short8*)&Vts[ks][srow][c8] = vreg[ks];
    __syncthreads();

    if (kt + 64 < S) {
#pragma unroll
      for (int hd = 0; hd < 2; hd++)
        kreg[hd] = *(const short8*)(Kst + (size_t)(kt + 64) * LDQ + hd * 32);
#pragma unroll
      for (int ks = 0; ks < 2; ks++)
        vreg[ks] = *(const short8*)(Vst + (kt + 64) + ks * 32);
    }

    short8 kf[4][2];
#pragma unroll
    for (int st = 0; st < 4; st++)
#pragma unroll
      for (int hd = 0; hd < 2; hd++)
        kf[st][hd] = *(const short8*)&Ks[hd][st * 16 + row16][oct * 8];

    float4v sc[2][4];
#pragma unroll
    for (int f = 0; f < 2; f++)
#pragma unroll
      for (int st = 0; st < 4; st++) {
        float4v s = {};
        s = __builtin_amdgcn_mfma_f32_16x16x32_bf16(qf[f][0], kf[st][0], s, 0, 0, 0);
        s = __builtin_amdgcn_mfma_f32_16x16x32_bf16(qf[f][1], kf[st][1], s, 0, 0, 0);
        sc[f][st] = s;
      }

    short8 vf[2][4];
#pragma unroll
    for (int ks = 0; ks < 2; ks++)
#pragma unroll
      for (int ni = 0; ni < 4; ni++)
        vf[ks][ni] = *(const short8*)&Vts[ks][ni * 16 + row16][oct * 8];

#pragma unroll
    for (int f = 0; f < 2; f++) {
      const int base = kt + row16 - wid * 32 - f * 16 - oct * 4 + 127;
#pragma unroll
      for (int r = 0; r < 4; r++) {
        const int i0 = base - r;
        float b0 = biasS[i0],      b1 = biasS[i0 + 16];
        float b2 = biasS[i0 + 32], b3 = biasS[i0 + 48];
        sc[f][0][r] = __builtin_amdgcn_exp2f(__builtin_fmaf(sc[f][0][r], L2E, b0));
        sc[f][1][r] = __builtin_amdgcn_exp2f(__builtin_fmaf(sc[f][1][r], L2E, b1));
        sc[f][2][r] = __builtin_amdgcn_exp2f(__builtin_fmaf(sc[f][2][r], L2E, b2));
        sc[f][3][r] = __builtin_amdgcn_exp2f(__builtin_fmaf(sc[f][3][r], L2E, b3));
      }
      if (f == 0) {
#pragma unroll
        for (int ks = 0; ks < 2; ks++)
#pragma unroll
          for (int r = 0; r < 4; r++) {
            uint32_t pk = (uint32_t)f2b_fast(sc[0][2 * ks][r]) |
                          ((uint32_t)f2b_fast(sc[0][2 * ks + 1][r]) << 16);
            *(uint32_t*)&Pl[wid][ks][oct * 4 + r][2 * row16] = pk;
          }
      }
    }
#pragma unroll
    for (int f = 0; f < 2; f++) {
      if (f == 1) {
#pragma unroll
        for (int ks = 0; ks < 2; ks++)
#pragma unroll
          for (int r = 0; r < 4; r++) {
            uint32_t pk = (uint32_t)f2b_fast(sc[1][2 * ks][r]) |
                          ((uint32_t)f2b_fast(sc[1][2 * ks + 1][r]) << 16);
            *(uint32_t*)&Pl[wid][ks][oct * 4 + r][2 * row16] = pk;
          }
      }
#pragma unroll
      for (int r = 0; r < 4; r++)
        l_r[f][r] += (sc[f][0][r] + sc[f][1][r]) + (sc[f][2][r] + sc[f][3][r]);
#pragma unroll
      for (int ks = 0; ks < 2; ks++) {
        short8 pf = *(const short8*)&Pl[wid][ks][row16][oct * 8];
#pragma unroll
        for (int ni = 0; ni < 4; ni++)
          o_acc[f][ni] = __builtin_amdgcn_mfma_f32_16x16x32_bf16(pf, vf[ks][ni], o_acc[f][ni], 0, 0, 0);
      }
    }
  }

#pragma unroll
  for (int f = 0; f < 2; f++) {
#pragma unroll
    for (int r = 0; r < 4; r++) {
      float v = l_r[f][r];
      v += __shfl_xor(v, 1); v += __shfl_xor(v, 2);
      v += __shfl_xor(v, 4); v += __shfl_xor(v, 8);
      l_r[f][r] = 1.0f / v;
    }
    const size_t orow = (size_t)b * S + qt0 + wid * 32 + f * 16 + oct * 4;
#pragma unroll
    for (int ni = 0; ni < 4; ni++)
#pragma unroll
      for (int r = 0; r < 4; r++)
        ctx[(orow + r) * 1024 + h * 64 + ni * 16 + row16] = f2b_fast(o_acc[f][ni][r] * l_r[f][r]);
  }
}

// ---------------- host launcher ------------------------------------------------
extern "C" void kernel_launch(void* const* d_in, const int* in_sizes, int n_in,
                              void* d_out, int out_size, void* d_ws, size_t ws_size,
                              hipStream_t stream) {
  const float* x        = (const float*)d_in[0];
  const float* q_w      = (const float*)d_in[1];
  const float* k_w      = (const float*)d_in[2];
  const float* v_w      = (const float*)d_in[3];
  const float* o_w      = (const float*)d_in[4];
  const float* rel_bias = (const float*)d_in[5];

  char* ws = (char*)d_ws;
  u16*   xb    = (u16*)(ws);                         // 8 MB
  u16*   wqkv  = (u16*)(ws + 8388608);               // 6 MB
  u16*   owb   = (u16*)(ws + 14680064);              // 2 MB
  u16*   qkvb  = (u16*)(ws + 16777216);              // 24 MB
  u16*   ctxb  = (u16*)(ws + 41943040);              // 8 MB
  float* biasT = (float*)(ws + 50331648);            // 256 KB
  u16*   vTp   = xb;                                 // reuse xb after QKV GEMM

  cvt_all<<<8192, 256, 0, stream>>>(x, q_w, k_w, v_w, o_w, xb, wqkv, owb);
  build_bias<<<256, 256, 0, stream>>>(rel_bias, biasT);

  dim3 g1(4096 / 128, 3072 / 128);
  gemm_bt<true><<<g1, 256, 0, stream>>>(xb, wqkv, qkvb, 1024, 3072);

  dim3 gt(2048 / 64, 16, 2);
  transpose_v<<<gt, 256, 0, stream>>>(qkvb, vTp);

  dim3 g2(2048 / 128, 16, 2);
  flash_attn<<<g2, 256, 0, stream>>>(qkvb, vTp, biasT, ctxb);

  dim3 g3(4096 / 128, 1024 / 128);
  gemm_bt<false><<<g3, 256, 0, stream>>>(ctxb, owb, d_out, 1024, 1024);
}

// Round 9
// 195.769 us; speedup vs baseline: 1.3499x; 1.0459x over previous
//
#include <hip/hip_runtime.h>
#include <stdint.h>

// T5-style attention, MI355X gfx950.
// B=2 S=2048 D=1024 H=16 DK=64, NUM_BUCKETS=32, MAX_DISTANCE=128.
// R9: GEMM K-loop BK=32 -> BK=64 (32 MFMA/iter, half the barriers; split
// k-half LDS [2][128][32] still global_load_lds-fed). build_bias merged
// into cvt_all. Flash = R6 verbatim (best known: 65.4us).

typedef unsigned short u16;
typedef __attribute__((ext_vector_type(8))) short short8;
typedef __attribute__((ext_vector_type(4))) float float4v;
typedef __attribute__((ext_vector_type(4))) u16 ushort4v;

typedef __attribute__((address_space(1))) void void_g;
typedef __attribute__((address_space(3))) void void_l;

#define L2E 1.4426950408889634f

__device__ __forceinline__ u16 f2b(float f) {
  union { float f; uint32_t u; } v; v.f = f;
  uint32_t r = (v.u + 0x7fffu + ((v.u >> 16) & 1u)) >> 16;
  return (u16)r;
}
__device__ __forceinline__ u16 f2b_fast(float f) {
  union { float f; uint32_t u; } v; v.f = f;
  return (u16)((v.u + 0x8000u) >> 16);
}

// ---------------- fused fp32->bf16 convert + bias table -------------------------
// blocks [0,8192): cvt regions; blocks [8192,8448): bias table.
// biasT[h][d+2047] = (bias - 8) * log2e
__global__ void cvt_all(const float* __restrict__ x,  const float* __restrict__ qw,
                        const float* __restrict__ kw, const float* __restrict__ vw,
                        const float* __restrict__ ow, const float* __restrict__ rel_bias,
                        u16* __restrict__ xb, u16* __restrict__ wqkv, u16* __restrict__ owb,
                        float* __restrict__ biasT) {
  int bi = blockIdx.x;
  if (bi >= 8192) {
    int idx = (bi - 8192) * 256 + threadIdx.x;   // 0..65535
    int h = idx >> 12, t = idx & 4095;
    if (t > 4094) { biasT[h * 4096 + 4095] = -1.0e4f; return; }
    int d = t - 2047;
    int n = -d;
    int ret = (n < 0) ? 16 : 0;
    int na = (n < 0) ? -n : n;
    int bucket;
    if (na < 8) {
      bucket = ret + na;
    } else {
      float v = logf((float)na / 8.0f) / logf(16.0f) * 8.0f;
      int vi = 8 + (int)v;
      bucket = ret + (vi > 15 ? 15 : vi);
    }
    biasT[h * 4096 + t] = (rel_bias[bucket * 16 + h] - 8.0f) * L2E;
    return;
  }
  int i = bi * 256 + threadIdx.x;
  const float* s; u16* d; int off;
  if (i < 1048576)      { s = x;  d = xb;              off = i; }
  else if (i < 1310720) { s = qw; d = wqkv;            off = i - 1048576; }
  else if (i < 1572864) { s = kw; d = wqkv + 1048576;  off = i - 1310720; }
  else if (i < 1835008) { s = vw; d = wqkv + 2097152;  off = i - 1572864; }
  else                  { s = ow; d = owb;             off = i - 1835008; }
  float4v v = ((const float4v*)s)[off];
  ushort4v o;
  o.x = f2b(v.x); o.y = f2b(v.y); o.z = f2b(v.z); o.w = f2b(v.w);
  ((ushort4v*)d)[off] = o;
}

// ---------------- bf16 GEMM: C[M,N] = A[M,K] * W[N,K]^T ------------------------
// 128x128 tile, BK=64: LDS As/Bs [2][128][32] (k-half split), 32 MFMA/iter.
// Epilogue staged through LDS for coalesced b128 stores.
template<bool OUT_BF16>
__global__ __launch_bounds__(256, 2)
void gemm_bt(const u16* __restrict__ A, const u16* __restrict__ W,
             void* __restrict__ Cp, int K, int N) {
  __shared__ __align__(16) char SM[34816];  // As 16K + Bs 16K; epilogue reuses
  u16* As = (u16*)SM;            // [kk][row][32]
  u16* Bs = (u16*)(SM + 16384);
  const int tid = threadIdx.x;
  const int wid = tid >> 6;
  const int lane = tid & 63;
  const int row16 = lane & 15, oct = lane >> 4;
  const int tm = blockIdx.x * 128, tn = blockIdx.y * 128;
  const int wm = (wid & 1) * 64, wn = (wid >> 1) * 64;
  const int srow = lane >> 2;        // 0..15 within a 16-row block
  const int sc = (lane & 3) * 8;     // elem offset within 32-wide k-half
  float4v acc[4][4] = {};
  for (int k0 = 0; k0 < K; k0 += 64) {
    __syncthreads();
#pragma unroll
    for (int i = 0; i < 4; i++) {
      const int idx = i * 4 + wid;   // 0..15
      const int kk = idx & 1;        // k-half
      const int rb = idx >> 1;       // row block 0..7
      const int r = rb * 16 + srow;
      const int c = kk * 32 + sc;
      // LDS dest wave-uniform base; lane writes base + lane*16B:
      // (kk*128 + rb*16 + (lane>>2))*32 + (lane&3)*8 = base + lane*8 elems
      __builtin_amdgcn_global_load_lds((void_g*)(A + (size_t)(tm + r) * K + k0 + c),
                                       (void_l*)(As + (kk * 128 + rb * 16) * 32), 16, 0, 0);
      __builtin_amdgcn_global_load_lds((void_g*)(W + (size_t)(tn + r) * K + k0 + c),
                                       (void_l*)(Bs + (kk * 128 + rb * 16) * 32), 16, 0, 0);
    }
    __syncthreads();
#pragma unroll
    for (int kk = 0; kk < 2; kk++) {
      short8 af[4], bfr[4];
#pragma unroll
      for (int mi = 0; mi < 4; mi++)
        af[mi] = *(const short8*)(As + (kk * 128 + wm + mi * 16 + row16) * 32 + oct * 8);
#pragma unroll
      for (int ni = 0; ni < 4; ni++)
        bfr[ni] = *(const short8*)(Bs + (kk * 128 + wn + ni * 16 + row16) * 32 + oct * 8);
#pragma unroll
      for (int mi = 0; mi < 4; mi++)
#pragma unroll
        for (int ni = 0; ni < 4; ni++)
          acc[mi][ni] = __builtin_amdgcn_mfma_f32_16x16x32_bf16(af[mi], bfr[ni], acc[mi][ni], 0, 0, 0);
    }
  }

  if (OUT_BF16) {
    // stage 128x128 bf16 tile in LDS (pitch 136), coalesced b128 out
    u16* Es = (u16*)SM;
    __syncthreads();
#pragma unroll
    for (int mi = 0; mi < 4; mi++)
#pragma unroll
      for (int ni = 0; ni < 4; ni++)
#pragma unroll
        for (int r = 0; r < 4; r++)
          Es[(wm + mi * 16 + oct * 4 + r) * 136 + wn + ni * 16 + row16] = f2b(acc[mi][ni][r]);
    __syncthreads();
    u16* C = (u16*)Cp;
#pragma unroll
    for (int it = 0; it < 8; it++) {
      int idx = it * 256 + tid;
      int row = idx >> 4, c = idx & 15;
      short8 v = *(const short8*)(Es + row * 136 + c * 8);
      *(short8*)(C + (size_t)(tm + row) * N + tn + c * 8) = v;
    }
  } else {
    // f32 out: two 64-row passes through LDS (pitch 132), coalesced dwordx4
    float* Ef = (float*)SM;
    float* C = (float*)Cp;
#pragma unroll
    for (int pass = 0; pass < 2; pass++) {
      __syncthreads();
      if ((wid & 1) == pass) {
#pragma unroll
        for (int mi = 0; mi < 4; mi++)
#pragma unroll
          for (int ni = 0; ni < 4; ni++)
#pragma unroll
            for (int r = 0; r < 4; r++)
              Ef[(mi * 16 + oct * 4 + r) * 132 + wn + ni * 16 + row16] = acc[mi][ni][r];
      }
      __syncthreads();
#pragma unroll
      for (int it = 0; it < 8; it++) {
        int idx = it * 256 + tid;
        int row = idx >> 5, c = idx & 31;
        float4v v = *(const float4v*)(Ef + row * 132 + c * 4);
        *(float4v*)(C + (size_t)(tm + pass * 64 + row) * N + tn + c * 4) = v;
      }
    }
  }
}

// ---------------- V transpose + k-permutation ----------------------------------
// QKV V-section [b][s][h*64+d] -> vTp[b][h][d][s'], kappa = 2*(s&15)+((s>>4)&1)
__global__ __launch_bounds__(256, 2)
void transpose_v(const u16* __restrict__ QKV, u16* __restrict__ vTp) {
  const int s0 = blockIdx.x * 64, h = blockIdx.y, b = blockIdx.z;
  const int tid = threadIdx.x;
  __shared__ u16 T[64 * 73];
  const u16* src = QKV + 2048 + (size_t)b * 2048 * 3072 + h * 64;
#pragma unroll
  for (int it = 0; it < 2; it++) {
    int idx = it * 256 + tid;
    int sl = idx >> 3;
    int c = idx & 7;
    short8 v = *(const short8*)(src + (size_t)(s0 + sl) * 3072 + c * 8);
#pragma unroll
    for (int k = 0; k < 8; k++) T[(c * 8 + k) * 73 + sl] = (u16)v[k];
  }
  __syncthreads();
  u16* dst = vTp + ((size_t)(b * 16 + h) * 64) * 2048 + s0;
#pragma unroll
  for (int it = 0; it < 2; it++) {
    int idx = it * 256 + tid;
    int d = idx >> 3;
    int cs = idx & 7;
    short8 o;
#pragma unroll
    for (int k = 0; k < 8; k++) {
      int sp = cs * 8 + k;
      int sl = (sp & 32) + 16 * (sp & 1) + ((sp & 31) >> 1);
      o[k] = (short)T[d * 73 + sl];
    }
    *(short8*)(dst + (size_t)d * 2048 + cs * 8) = o;
  }
}

// ---------------- flash attention (R6 verbatim) --------------------------------
__global__ __launch_bounds__(256, 2)
void flash_attn(const u16* __restrict__ QKV, const u16* __restrict__ vTp,
                const float* __restrict__ biasT, u16* __restrict__ ctx) {
  const int S = 2048, LDQ = 3072;
  const int qt0 = blockIdx.x * 128;
  const int h = blockIdx.y, b = blockIdx.z;
  const int tid = threadIdx.x, wid = tid >> 6, lane = tid & 63;
  const int row16 = lane & 15, oct = lane >> 4;

  __shared__ __align__(16) float biasS[2176];
  __shared__ __align__(16) u16 Ks[2][64][40];
  __shared__ __align__(16) u16 Vts[2][64][40];
  __shared__ __align__(16) u16 Pl[4][2][16][40];

  {
    const float* bsrc = biasT + h * 4096 + (1920 - qt0);
    for (int i = tid; i < 544; i += 256)
      ((float4v*)biasS)[i] = ((const float4v*)bsrc)[i];
  }

  const u16* qbase = QKV + ((size_t)b * S + qt0 + wid * 32) * LDQ + h * 64;
  short8 qf[2][2];
#pragma unroll
  for (int f = 0; f < 2; f++)
#pragma unroll
    for (int hd = 0; hd < 2; hd++)
      qf[f][hd] = *(const short8*)(qbase + (size_t)(f * 16 + row16) * LDQ + hd * 32 + oct * 8);

  float l_r[2][4] = {};
  float4v o_acc[2][4] = {};

  const int sr = lane >> 2, c8 = (lane & 3) * 8;
  const int srow = wid * 16 + sr;
  const u16* Kst = QKV + 1024 + ((size_t)b * S + srow) * LDQ + h * 64 + c8;
  const u16* Vst = vTp + ((size_t)(b * 16 + h) * 64 + srow) * 2048 + c8;

  short8 kreg[2], vreg[2];
#pragma unroll
  for (int hd = 0; hd < 2; hd++) kreg[hd] = *(const short8*)(Kst + hd * 32);
#pragma unroll
  for (int ks = 0; ks < 2; ks++) vreg[ks] = *(const short8*)(Vst + ks * 32);

  for (int kt = 0; kt < S; kt += 64) {
    __syncthreads();
#pragma unroll
    for (int hd = 0; hd < 2; hd++) *(short8*)&Ks[hd][srow][c8] = kreg[hd];
#pragma unroll
    for (int ks = 0; ks < 2; ks++) *(short8*)&Vts[ks][srow][c8] = vreg[ks];
    __syncthreads();

    if (kt + 64 < S) {
#pragma unroll
      for (int hd = 0; hd < 2; hd++)
        kreg[hd] = *(const short8*)(Kst + (size_t)(kt + 64) * LDQ + hd * 32);
#pragma unroll
      for (int ks = 0; ks < 2; ks++)
        vreg[ks] = *(const short8*)(Vst + (kt + 64) + ks * 32);
    }

    short8 kf[4][2];
#pragma unroll
    for (int st = 0; st < 4; st++)
#pragma unroll
      for (int hd = 0; hd < 2; hd++)
        kf[st][hd] = *(const short8*)&Ks[hd][st * 16 + row16][oct * 8];

    float4v sc[2][4];
#pragma unroll
    for (int f = 0; f < 2; f++)
#pragma unroll
      for (int st = 0; st < 4; st++) {
        float4v s = {};
        s = __builtin_amdgcn_mfma_f32_16x16x32_bf16(qf[f][0], kf[st][0], s, 0, 0, 0);
        s = __builtin_amdgcn_mfma_f32_16x16x32_bf16(qf[f][1], kf[st][1], s, 0, 0, 0);
        sc[f][st] = s;
      }

    short8 vf[2][4];
#pragma unroll
    for (int ks = 0; ks < 2; ks++)
#pragma unroll
      for (int ni = 0; ni < 4; ni++)
        vf[ks][ni] = *(const short8*)&Vts[ks][ni * 16 + row16][oct * 8];

#pragma unroll
    for (int f = 0; f < 2; f++) {
      const int base = kt + row16 - wid * 32 - f * 16 - oct * 4 + 127;
#pragma unroll
      for (int r = 0; r < 4; r++) {
        const int i0 = base - r;
        float b0 = biasS[i0],      b1 = biasS[i0 + 16];
        float b2 = biasS[i0 + 32], b3 = biasS[i0 + 48];
        sc[f][0][r] = __builtin_amdgcn_exp2f(__builtin_fmaf(sc[f][0][r], L2E, b0));
        sc[f][1][r] = __builtin_amdgcn_exp2f(__builtin_fmaf(sc[f][1][r], L2E, b1));
        sc[f][2][r] = __builtin_amdgcn_exp2f(__builtin_fmaf(sc[f][2][r], L2E, b2));
        sc[f][3][r] = __builtin_amdgcn_exp2f(__builtin_fmaf(sc[f][3][r], L2E, b3));
      }
      if (f == 0) {
#pragma unroll
        for (int ks = 0; ks < 2; ks++)
#pragma unroll
          for (int r = 0; r < 4; r++) {
            uint32_t pk = (uint32_t)f2b_fast(sc[0][2 * ks][r]) |
                          ((uint32_t)f2b_fast(sc[0][2 * ks + 1][r]) << 16);
            *(uint32_t*)&Pl[wid][ks][oct * 4 + r][2 * row16] = pk;
          }
      }
    }
#pragma unroll
    for (int f = 0; f < 2; f++) {
      if (f == 1) {
#pragma unroll
        for (int ks = 0; ks < 2; ks++)
#pragma unroll
          for (int r = 0; r < 4; r++) {
            uint32_t pk = (uint32_t)f2b_fast(sc[1][2 * ks][r]) |
                          ((uint32_t)f2b_fast(sc[1][2 * ks + 1][r]) << 16);
            *(uint32_t*)&Pl[wid][ks][oct * 4 + r][2 * row16] = pk;
          }
      }
#pragma unroll
      for (int r = 0; r < 4; r++)
        l_r[f][r] += (sc[f][0][r] + sc[f][1][r]) + (sc[f][2][r] + sc[f][3][r]);
#pragma unroll
      for (int ks = 0; ks < 2; ks++) {
        short8 pf = *(const short8*)&Pl[wid][ks][row16][oct * 8];
#pragma unroll
        for (int ni = 0; ni < 4; ni++)
          o_acc[f][ni] = __builtin_amdgcn_mfma_f32_16x16x32_bf16(pf, vf[ks][ni], o_acc[f][ni], 0, 0, 0);
      }
    }
  }

#pragma unroll
  for (int f = 0; f < 2; f++) {
#pragma unroll
    for (int r = 0; r < 4; r++) {
      float v = l_r[f][r];
      v += __shfl_xor(v, 1); v += __shfl_xor(v, 2);
      v += __shfl_xor(v, 4); v += __shfl_xor(v, 8);
      l_r[f][r] = 1.0f / v;
    }
    const size_t orow = (size_t)b * S + qt0 + wid * 32 + f * 16 + oct * 4;
#pragma unroll
    for (int ni = 0; ni < 4; ni++)
#pragma unroll
      for (int r = 0; r < 4; r++)
        ctx[(orow + r) * 1024 + h * 64 + ni * 16 + row16] = f2b_fast(o_acc[f][ni][r] * l_r[f][r]);
  }
}

// ---------------- host launcher ------------------------------------------------
extern "C" void kernel_launch(void* const* d_in, const int* in_sizes, int n_in,
                              void* d_out, int out_size, void* d_ws, size_t ws_size,
                              hipStream_t stream) {
  const float* x        = (const float*)d_in[0];
  const float* q_w      = (const float*)d_in[1];
  const float* k_w      = (const float*)d_in[2];
  const float* v_w      = (const float*)d_in[3];
  const float* o_w      = (const float*)d_in[4];
  const float* rel_bias = (const float*)d_in[5];

  char* ws = (char*)d_ws;
  u16*   xb    = (u16*)(ws);                         // 8 MB
  u16*   wqkv  = (u16*)(ws + 8388608);               // 6 MB
  u16*   owb   = (u16*)(ws + 14680064);              // 2 MB
  u16*   qkvb  = (u16*)(ws + 16777216);              // 24 MB
  u16*   ctxb  = (u16*)(ws + 41943040);              // 8 MB
  float* biasT = (float*)(ws + 50331648);            // 256 KB
  u16*   vTp   = xb;                                 // reuse xb after QKV GEMM

  cvt_all<<<8448, 256, 0, stream>>>(x, q_w, k_w, v_w, o_w, rel_bias,
                                    xb, wqkv, owb, biasT);

  dim3 g1(4096 / 128, 3072 / 128);
  gemm_bt<true><<<g1, 256, 0, stream>>>(xb, wqkv, qkvb, 1024, 3072);

  dim3 gt(2048 / 64, 16, 2);
  transpose_v<<<gt, 256, 0, stream>>>(qkvb, vTp);

  dim3 g2(2048 / 128, 16, 2);
  flash_attn<<<g2, 256, 0, stream>>>(qkvb, vTp, biasT, ctxb);

  dim3 g3(4096 / 128, 1024 / 128);
  gemm_bt<false><<<g3, 256, 0, stream>>>(ctxb, owb, d_out, 1024, 1024);
}

// Round 11
// 195.543 us; speedup vs baseline: 1.3514x; 1.0012x over previous
//
#include <hip/hip_runtime.h>
#include <stdint.h>

// T5-style attention, MI355X gfx950.
// B=2 S=2048 D=1024 H=16 DK=64, NUM_BUCKETS=32, MAX_DISTANCE=128.
// R11: R10 with compile fix ((float*)d_out cast). (1) flash far-tile
// constant-bias short-circuit; (2) transpose_v fused into QKV-GEMM epilogue;
// Q/K in dedicated qkb (LDC=2048). GEMM BK=64. Flash core = R6.

typedef unsigned short u16;
typedef __attribute__((ext_vector_type(8))) short short8;
typedef __attribute__((ext_vector_type(4))) float float4v;
typedef __attribute__((ext_vector_type(4))) u16 ushort4v;

typedef __attribute__((address_space(1))) void void_g;
typedef __attribute__((address_space(3))) void void_l;

#define L2E 1.4426950408889634f

__device__ __forceinline__ u16 f2b(float f) {
  union { float f; uint32_t u; } v; v.f = f;
  uint32_t r = (v.u + 0x7fffu + ((v.u >> 16) & 1u)) >> 16;
  return (u16)r;
}
__device__ __forceinline__ u16 f2b_fast(float f) {
  union { float f; uint32_t u; } v; v.f = f;
  return (u16)((v.u + 0x8000u) >> 16);
}

// ---------------- fused fp32->bf16 convert + bias table -------------------------
// blocks [0,8192): cvt regions; blocks [8192,8448): bias table.
// biasT[h][d+2047] = (bias - 8) * log2e
__global__ void cvt_all(const float* __restrict__ x,  const float* __restrict__ qw,
                        const float* __restrict__ kw, const float* __restrict__ vw,
                        const float* __restrict__ ow, const float* __restrict__ rel_bias,
                        u16* __restrict__ xb, u16* __restrict__ wqkv, u16* __restrict__ owb,
                        float* __restrict__ biasT) {
  int bi = blockIdx.x;
  if (bi >= 8192) {
    int idx = (bi - 8192) * 256 + threadIdx.x;   // 0..65535
    int h = idx >> 12, t = idx & 4095;
    if (t > 4094) { biasT[h * 4096 + 4095] = -1.0e4f; return; }
    int d = t - 2047;
    int n = -d;
    int ret = (n < 0) ? 16 : 0;
    int na = (n < 0) ? -n : n;
    int bucket;
    if (na < 8) {
      bucket = ret + na;
    } else {
      float v = logf((float)na / 8.0f) / logf(16.0f) * 8.0f;
      int vi = 8 + (int)v;
      bucket = ret + (vi > 15 ? 15 : vi);
    }
    biasT[h * 4096 + t] = (rel_bias[bucket * 16 + h] - 8.0f) * L2E;
    return;
  }
  int i = bi * 256 + threadIdx.x;
  const float* s; u16* d; int off;
  if (i < 1048576)      { s = x;  d = xb;              off = i; }
  else if (i < 1310720) { s = qw; d = wqkv;            off = i - 1048576; }
  else if (i < 1572864) { s = kw; d = wqkv + 1048576;  off = i - 1310720; }
  else if (i < 1835008) { s = vw; d = wqkv + 2097152;  off = i - 1572864; }
  else                  { s = ow; d = owb;             off = i - 1835008; }
  float4v v = ((const float4v*)s)[off];
  ushort4v o;
  o.x = f2b(v.x); o.y = f2b(v.y); o.z = f2b(v.z); o.w = f2b(v.w);
  ((ushort4v*)d)[off] = o;
}

// ---------------- QKV GEMM: [4096,3072] = xb[4096,1024] * wqkv[3072,1024]^T ----
// 128x128 tile, BK=64. Epilogue: Q/K cols (tn<2048) -> qkb row-major LDC=2048;
// V cols (tn>=2048) -> vTp[b][h][d][s'] transposed + kappa-permuted.
__global__ __launch_bounds__(256, 2)
void gemm_qkv(const u16* __restrict__ A, const u16* __restrict__ W,
              u16* __restrict__ qkb, u16* __restrict__ vTp) {
  const int K = 1024;
  __shared__ __align__(16) char SM[34816];
  u16* As = (u16*)SM;            // [kk][row][32]
  u16* Bs = (u16*)(SM + 16384);
  const int tid = threadIdx.x;
  const int wid = tid >> 6;
  const int lane = tid & 63;
  const int row16 = lane & 15, oct = lane >> 4;
  const int tm = blockIdx.x * 128, tn = blockIdx.y * 128;
  const int wm = (wid & 1) * 64, wn = (wid >> 1) * 64;
  const int srow = lane >> 2;
  const int sc = (lane & 3) * 8;
  float4v acc[4][4] = {};
  for (int k0 = 0; k0 < K; k0 += 64) {
    __syncthreads();
#pragma unroll
    for (int i = 0; i < 4; i++) {
      const int idx = i * 4 + wid;
      const int kk = idx & 1;
      const int rb = idx >> 1;
      const int r = rb * 16 + srow;
      const int c = kk * 32 + sc;
      __builtin_amdgcn_global_load_lds((void_g*)(A + (size_t)(tm + r) * K + k0 + c),
                                       (void_l*)(As + (kk * 128 + rb * 16) * 32), 16, 0, 0);
      __builtin_amdgcn_global_load_lds((void_g*)(W + (size_t)(tn + r) * K + k0 + c),
                                       (void_l*)(Bs + (kk * 128 + rb * 16) * 32), 16, 0, 0);
    }
    __syncthreads();
#pragma unroll
    for (int kk = 0; kk < 2; kk++) {
      short8 af[4], bfr[4];
#pragma unroll
      for (int mi = 0; mi < 4; mi++)
        af[mi] = *(const short8*)(As + (kk * 128 + wm + mi * 16 + row16) * 32 + oct * 8);
#pragma unroll
      for (int ni = 0; ni < 4; ni++)
        bfr[ni] = *(const short8*)(Bs + (kk * 128 + wn + ni * 16 + row16) * 32 + oct * 8);
#pragma unroll
      for (int mi = 0; mi < 4; mi++)
#pragma unroll
        for (int ni = 0; ni < 4; ni++)
          acc[mi][ni] = __builtin_amdgcn_mfma_f32_16x16x32_bf16(af[mi], bfr[ni], acc[mi][ni], 0, 0, 0);
    }
  }

  // stage 128x128 bf16 tile in LDS (pitch 136)
  u16* Es = (u16*)SM;
  __syncthreads();
#pragma unroll
  for (int mi = 0; mi < 4; mi++)
#pragma unroll
    for (int ni = 0; ni < 4; ni++)
#pragma unroll
      for (int r = 0; r < 4; r++)
        Es[(wm + mi * 16 + oct * 4 + r) * 136 + wn + ni * 16 + row16] = f2b(acc[mi][ni][r]);
  __syncthreads();

  if (tn < 2048) {
    // Q/K: row-major into qkb, LDC=2048
#pragma unroll
    for (int it = 0; it < 8; it++) {
      int idx = it * 256 + tid;
      int row = idx >> 4, c = idx & 15;
      short8 v = *(const short8*)(Es + row * 136 + c * 8);
      *(short8*)(qkb + (size_t)(tm + row) * 2048 + tn + c * 8) = v;
    }
  } else {
    // V: transposed + kappa-permuted into vTp[b][h][d][s']
    const int h0 = (tn - 2048) >> 6;     // head of cols 0..63 (h0+1 for 64..127)
    const int b = tm >> 11;
    const int s0 = tm & 2047;
#pragma unroll
    for (int it = 0; it < 8; it++) {
      int idx = it * 256 + tid;
      int dg = idx >> 4;                  // 0..127 (col within tile)
      int ch = idx & 15;                  // 8-elem s' chunk
      short8 o;
#pragma unroll
      for (int j = 0; j < 8; j++) {
        int sp = ch * 8 + j;              // s' local 0..127
        int sl = (sp & ~31) + 16 * (sp & 1) + ((sp & 31) >> 1);  // orig s local
        o[j] = (short)Es[sl * 136 + dg];
      }
      const int head = h0 + (dg >> 6), d = dg & 63;
      *(short8*)(vTp + ((size_t)((b * 16 + head) * 64 + d)) * 2048 + s0 + ch * 8) = o;
    }
  }
}

// ---------------- out GEMM: d_out[4096,1024] = ctxb * owb^T (f32 out) ----------
__global__ __launch_bounds__(256, 2)
void gemm_out(const u16* __restrict__ A, const u16* __restrict__ W,
              float* __restrict__ C) {
  const int K = 1024, N = 1024;
  __shared__ __align__(16) char SM[34816];
  u16* As = (u16*)SM;
  u16* Bs = (u16*)(SM + 16384);
  const int tid = threadIdx.x;
  const int wid = tid >> 6;
  const int lane = tid & 63;
  const int row16 = lane & 15, oct = lane >> 4;
  const int tm = blockIdx.x * 128, tn = blockIdx.y * 128;
  const int wm = (wid & 1) * 64, wn = (wid >> 1) * 64;
  const int srow = lane >> 2;
  const int sc = (lane & 3) * 8;
  float4v acc[4][4] = {};
  for (int k0 = 0; k0 < K; k0 += 64) {
    __syncthreads();
#pragma unroll
    for (int i = 0; i < 4; i++) {
      const int idx = i * 4 + wid;
      const int kk = idx & 1;
      const int rb = idx >> 1;
      const int r = rb * 16 + srow;
      const int c = kk * 32 + sc;
      __builtin_amdgcn_global_load_lds((void_g*)(A + (size_t)(tm + r) * K + k0 + c),
                                       (void_l*)(As + (kk * 128 + rb * 16) * 32), 16, 0, 0);
      __builtin_amdgcn_global_load_lds((void_g*)(W + (size_t)(tn + r) * K + k0 + c),
                                       (void_l*)(Bs + (kk * 128 + rb * 16) * 32), 16, 0, 0);
    }
    __syncthreads();
#pragma unroll
    for (int kk = 0; kk < 2; kk++) {
      short8 af[4], bfr[4];
#pragma unroll
      for (int mi = 0; mi < 4; mi++)
        af[mi] = *(const short8*)(As + (kk * 128 + wm + mi * 16 + row16) * 32 + oct * 8);
#pragma unroll
      for (int ni = 0; ni < 4; ni++)
        bfr[ni] = *(const short8*)(Bs + (kk * 128 + wn + ni * 16 + row16) * 32 + oct * 8);
#pragma unroll
      for (int mi = 0; mi < 4; mi++)
#pragma unroll
        for (int ni = 0; ni < 4; ni++)
          acc[mi][ni] = __builtin_amdgcn_mfma_f32_16x16x32_bf16(af[mi], bfr[ni], acc[mi][ni], 0, 0, 0);
    }
  }
  // f32 out: two 64-row passes through LDS (pitch 132), coalesced dwordx4
  float* Ef = (float*)SM;
#pragma unroll
  for (int pass = 0; pass < 2; pass++) {
    __syncthreads();
    if ((wid & 1) == pass) {
#pragma unroll
      for (int mi = 0; mi < 4; mi++)
#pragma unroll
        for (int ni = 0; ni < 4; ni++)
#pragma unroll
          for (int r = 0; r < 4; r++)
            Ef[(mi * 16 + oct * 4 + r) * 132 + wn + ni * 16 + row16] = acc[mi][ni][r];
    }
    __syncthreads();
#pragma unroll
    for (int it = 0; it < 8; it++) {
      int idx = it * 256 + tid;
      int row = idx >> 5, c = idx & 31;
      float4v v = *(const float4v*)(Ef + row * 132 + c * 4);
      *(float4v*)(C + (size_t)(tm + pass * 64 + row) * N + tn + c * 4) = v;
    }
  }
}

// ---------------- flash attention ----------------------------------------------
// grid (S/128, H, B), block 256 = 4 waves; wave owns 32 q-rows (2 q-frags).
// KT=64. Static softmax max 8, exp2-folded bias. Far tiles (|k-q|>=128 across
// the whole tile) use a block-uniform constant bias (bucket saturated).
__global__ __launch_bounds__(256, 2)
void flash_attn(const u16* __restrict__ qkb, const u16* __restrict__ vTp,
                const float* __restrict__ biasT, u16* __restrict__ ctx) {
  const int S = 2048, LDQ = 2048;
  const int qt0 = blockIdx.x * 128;
  const int h = blockIdx.y, b = blockIdx.z;
  const int tid = threadIdx.x, wid = tid >> 6, lane = tid & 63;
  const int row16 = lane & 15, oct = lane >> 4;

  __shared__ __align__(16) float biasS[2176];
  __shared__ __align__(16) u16 Ks[2][64][40];
  __shared__ __align__(16) u16 Vts[2][64][40];
  __shared__ __align__(16) u16 Pl[4][2][16][40];

  {
    const float* bsrc = biasT + h * 4096 + (1920 - qt0);
    for (int i = tid; i < 544; i += 256)
      ((float4v*)biasS)[i] = ((const float4v*)bsrc)[i];
  }
  const float bias_neg = biasT[h * 4096];          // d <= -128 (bucket 15)
  const float bias_pos = biasT[h * 4096 + 4094];   // d >= +128 (bucket 31)

  const u16* qbase = qkb + ((size_t)b * S + qt0 + wid * 32) * LDQ + h * 64;
  short8 qf[2][2];
#pragma unroll
  for (int f = 0; f < 2; f++)
#pragma unroll
    for (int hd = 0; hd < 2; hd++)
      qf[f][hd] = *(const short8*)(qbase + (size_t)(f * 16 + row16) * LDQ + hd * 32 + oct * 8);

  float l_r[2][4] = {};
  float4v o_acc[2][4] = {};

  const int sr = lane >> 2, c8 = (lane & 3) * 8;
  const int srow = wid * 16 + sr;
  const u16* Kst = qkb + 1024 + ((size_t)b * S + srow) * LDQ + c8 + h * 64;
  const u16* Vst = vTp + ((size_t)(b * 16 + h) * 64 + srow) * 2048 + c8;

  short8 kreg[2], vreg[2];
#pragma unroll
  for (int hd = 0; hd < 2; hd++) kreg[hd] = *(const short8*)(Kst + hd * 32);
#pragma unroll
  for (int ks = 0; ks < 2; ks++) vreg[ks] = *(const short8*)(Vst + ks * 32);

  for (int kt = 0; kt < S; kt += 64) {
    __syncthreads();
#pragma unroll
    for (int hd = 0; hd < 2; hd++) *(short8*)&Ks[hd][srow][c8] = kreg[hd];
#pragma unroll
    for (int ks = 0; ks < 2; ks++) *(short8*)&Vts[ks][srow][c8] = vreg[ks];
    __syncthreads();

    if (kt + 64 < S) {
#pragma unroll
      for (int hd = 0; hd < 2; hd++)
        kreg[hd] = *(const short8*)(Kst + (size_t)(kt + 64) * LDQ + hd * 32);
#pragma unroll
      for (int ks = 0; ks < 2; ks++)
        vreg[ks] = *(const short8*)(Vst + (kt + 64) + ks * 32);
    }

    short8 kf[4][2];
#pragma unroll
    for (int st = 0; st < 4; st++)
#pragma unroll
      for (int hd = 0; hd < 2; hd++)
        kf[st][hd] = *(const short8*)&Ks[hd][st * 16 + row16][oct * 8];

    float4v sc[2][4];
#pragma unroll
    for (int f = 0; f < 2; f++)
#pragma unroll
      for (int st = 0; st < 4; st++) {
        float4v s = {};
        s = __builtin_amdgcn_mfma_f32_16x16x32_bf16(qf[f][0], kf[st][0], s, 0, 0, 0);
        s = __builtin_amdgcn_mfma_f32_16x16x32_bf16(qf[f][1], kf[st][1], s, 0, 0, 0);
        sc[f][st] = s;
      }

    short8 vf[2][4];
#pragma unroll
    for (int ks = 0; ks < 2; ks++)
#pragma unroll
      for (int ni = 0; ni < 4; ni++)
        vf[ks][ni] = *(const short8*)&Vts[ks][ni * 16 + row16][oct * 8];

    // bias + exp: far tiles (bucket saturated) use block-uniform constant
    const int dk = kt - qt0;
    const bool far = (dk >= 256) || (dk <= -192);
    if (far) {
      const float bc = (dk > 0) ? bias_pos : bias_neg;
#pragma unroll
      for (int f = 0; f < 2; f++)
#pragma unroll
        for (int st = 0; st < 4; st++)
#pragma unroll
          for (int r = 0; r < 4; r++)
            sc[f][st][r] = __builtin_amdgcn_exp2f(__builtin_fmaf(sc[f][st][r], L2E, bc));
    } else {
#pragma unroll
      for (int f = 0; f < 2; f++) {
        const int base = kt + row16 - wid * 32 - f * 16 - oct * 4 + 127;
#pragma unroll
        for (int r = 0; r < 4; r++) {
          const int i0 = base - r;
          float b0 = biasS[i0],      b1 = biasS[i0 + 16];
          float b2 = biasS[i0 + 32], b3 = biasS[i0 + 48];
          sc[f][0][r] = __builtin_amdgcn_exp2f(__builtin_fmaf(sc[f][0][r], L2E, b0));
          sc[f][1][r] = __builtin_amdgcn_exp2f(__builtin_fmaf(sc[f][1][r], L2E, b1));
          sc[f][2][r] = __builtin_amdgcn_exp2f(__builtin_fmaf(sc[f][2][r], L2E, b2));
          sc[f][3][r] = __builtin_amdgcn_exp2f(__builtin_fmaf(sc[f][3][r], L2E, b3));
        }
      }
    }

    // P-store f0 first, then interleaved l/PV (R6 ordering)
#pragma unroll
    for (int ks = 0; ks < 2; ks++)
#pragma unroll
      for (int r = 0; r < 4; r++) {
        uint32_t pk = (uint32_t)f2b_fast(sc[0][2 * ks][r]) |
                      ((uint32_t)f2b_fast(sc[0][2 * ks + 1][r]) << 16);
        *(uint32_t*)&Pl[wid][ks][oct * 4 + r][2 * row16] = pk;
      }
#pragma unroll
    for (int f = 0; f < 2; f++) {
      if (f == 1) {
#pragma unroll
        for (int ks = 0; ks < 2; ks++)
#pragma unroll
          for (int r = 0; r < 4; r++) {
            uint32_t pk = (uint32_t)f2b_fast(sc[1][2 * ks][r]) |
                          ((uint32_t)f2b_fast(sc[1][2 * ks + 1][r]) << 16);
            *(uint32_t*)&Pl[wid][ks][oct * 4 + r][2 * row16] = pk;
          }
      }
#pragma unroll
      for (int r = 0; r < 4; r++)
        l_r[f][r] += (sc[f][0][r] + sc[f][1][r]) + (sc[f][2][r] + sc[f][3][r]);
#pragma unroll
      for (int ks = 0; ks < 2; ks++) {
        short8 pf = *(const short8*)&Pl[wid][ks][row16][oct * 8];
#pragma unroll
        for (int ni = 0; ni < 4; ni++)
          o_acc[f][ni] = __builtin_amdgcn_mfma_f32_16x16x32_bf16(pf, vf[ks][ni], o_acc[f][ni], 0, 0, 0);
      }
    }
  }

#pragma unroll
  for (int f = 0; f < 2; f++) {
#pragma unroll
    for (int r = 0; r < 4; r++) {
      float v = l_r[f][r];
      v += __shfl_xor(v, 1); v += __shfl_xor(v, 2);
      v += __shfl_xor(v, 4); v += __shfl_xor(v, 8);
      l_r[f][r] = 1.0f / v;
    }
    const size_t orow = (size_t)b * S + qt0 + wid * 32 + f * 16 + oct * 4;
#pragma unroll
    for (int ni = 0; ni < 4; ni++)
#pragma unroll
      for (int r = 0; r < 4; r++)
        ctx[(orow + r) * 1024 + h * 64 + ni * 16 + row16] = f2b_fast(o_acc[f][ni][r] * l_r[f][r]);
  }
}

// ---------------- host launcher ------------------------------------------------
extern "C" void kernel_launch(void* const* d_in, const int* in_sizes, int n_in,
                              void* d_out, int out_size, void* d_ws, size_t ws_size,
                              hipStream_t stream) {
  const float* x        = (const float*)d_in[0];
  const float* q_w      = (const float*)d_in[1];
  const float* k_w      = (const float*)d_in[2];
  const float* v_w      = (const float*)d_in[3];
  const float* o_w      = (const float*)d_in[4];
  const float* rel_bias = (const float*)d_in[5];

  char* ws = (char*)d_ws;
  u16*   xb    = (u16*)(ws);                         // [0,8M)   x bf16
  u16*   wqkv  = (u16*)(ws + 8388608);               // [8M,14M) qkv weights bf16
  u16*   owb   = (u16*)(ws + 14680064);              // [14M,16M) o_w bf16
  u16*   qkb   = (u16*)(ws + 16777216);              // [16M,32M) Q|K rows, LDC=2048
  u16*   vTp   = (u16*)(ws + 33554432);              // [32M,40M) V^T permuted
  u16*   ctxb  = (u16*)(ws + 41943040);              // [40M,48M) attention out bf16
  float* biasT = (float*)(ws + 50331648);            // [48M..] bias table

  cvt_all<<<8448, 256, 0, stream>>>(x, q_w, k_w, v_w, o_w, rel_bias,
                                    xb, wqkv, owb, biasT);

  dim3 g1(4096 / 128, 3072 / 128);
  gemm_qkv<<<g1, 256, 0, stream>>>(xb, wqkv, qkb, vTp);

  dim3 g2(2048 / 128, 16, 2);
  flash_attn<<<g2, 256, 0, stream>>>(qkb, vTp, biasT, ctxb);

  dim3 g3(4096 / 128, 1024 / 128);
  gemm_out<<<g3, 256, 0, stream>>>(ctxb, owb, (float*)d_out);
}